// Round 10
// baseline (240.340 us; speedup 1.0000x reference)
//
#include <hip/hip_runtime.h>
#include <stdint.h>

// Problem dims
#define TOKENS 8192      // 4*2048
#define IN_F   3072
#define PAD_F  4096
#define N_OUT  4096
#define K_DIM  4096

using i32x4 = __attribute__((ext_vector_type(4))) int;

// -------- workspace layout (bytes) --------
#define Q_OFF    0
#define WQ_OFF   33554432
#define AINV_OFF 50331648
#define PART_OFF 50364416
#define WSC_OFF  50380800

__device__ __forceinline__ void gload_lds16(const void* g, void* l) {
    __builtin_amdgcn_global_load_lds(
        (__attribute__((address_space(1))) void*)(void*)g,
        (__attribute__((address_space(3))) void*)l,
        16, 0, 0);
}

// ---------------- weight absmean: partial sums ----------------
__global__ __launch_bounds__(256) void k_wabs(const float* __restrict__ w,
                                              float* __restrict__ partial) {
    int tid = threadIdx.x;
    const float4* w4 = (const float4*)(w + (size_t)blockIdx.x * 4096);
    float s = 0.f;
#pragma unroll
    for (int i = 0; i < 4; ++i) {
        float4 v = w4[tid + i * 256];
        s += fabsf(v.x) + fabsf(v.y) + fabsf(v.z) + fabsf(v.w);
    }
#pragma unroll
    for (int o = 32; o > 0; o >>= 1) s += __shfl_xor(s, o);
    __shared__ float rb[4];
    if ((tid & 63) == 0) rb[tid >> 6] = s;
    __syncthreads();
    if (tid == 0) partial[blockIdx.x] = rb[0] + rb[1] + rb[2] + rb[3];
}

// ---------------- finalize weight scale ----------------
__global__ __launch_bounds__(256) void k_wscale(const float* __restrict__ partial,
                                                float* __restrict__ wsp) {
    int tid = threadIdx.x;
    float s = 0.f;
#pragma unroll
    for (int i = 0; i < 16; ++i) s += partial[tid + i * 256];
#pragma unroll
    for (int o = 32; o > 0; o >>= 1) s += __shfl_xor(s, o);
    __shared__ float rb[4];
    if ((tid & 63) == 0) rb[tid >> 6] = s;
    __syncthreads();
    if (tid == 0)
        wsp[0] = fmaxf((rb[0] + rb[1] + rb[2] + rb[3]) * (1.0f / 16777216.0f), 1e-5f);
}

// ---------------- ternary weight quant ----------------
__global__ __launch_bounds__(256) void k_wquant(const float* __restrict__ w,
                                                const float* __restrict__ wsp,
                                                unsigned int* __restrict__ wq) {
    int idx = blockIdx.x * 256 + threadIdx.x;   // float4 group index
    float ws = wsp[0];
    float4 v = ((const float4*)w)[idx];
    int a = (int)rintf(v.x / ws); a = max(-1, min(1, a));
    int b = (int)rintf(v.y / ws); b = max(-1, min(1, b));
    int c = (int)rintf(v.z / ws); c = max(-1, min(1, c));
    int d = (int)rintf(v.w / ws); d = max(-1, min(1, d));
    unsigned int p = (unsigned)(a & 255) | ((unsigned)(b & 255) << 8) |
                     ((unsigned)(c & 255) << 16) | ((unsigned)(d & 255) << 24);
    wq[idx] = p;
}

// ---------------- fused LayerNorm + pad + FWHT + int8 absmax quant ----------------
__global__ __launch_bounds__(256) void k_lnfwht(const float* __restrict__ x,
                                                const float* __restrict__ gamma,
                                                const float* __restrict__ beta,
                                                signed char* __restrict__ q,
                                                float* __restrict__ ainv) {
    __shared__ float s[PAD_F];
    __shared__ float rb[8];
    int tid = threadIdx.x;
    int lane = tid & 63;
    int t = blockIdx.x;
    const float* xr = x + (size_t)t * IN_F;

    float v[16];
    float sum = 0.f;
#pragma unroll
    for (int i = 0; i < 12; ++i) { v[i] = xr[tid + i * 256]; sum += v[i]; }
    v[12] = v[13] = v[14] = v[15] = 0.f;
#pragma unroll
    for (int o = 32; o > 0; o >>= 1) sum += __shfl_xor(sum, o);
    if ((tid & 63) == 0) rb[tid >> 6] = sum;
    __syncthreads();
    float mu = (rb[0] + rb[1] + rb[2] + rb[3]) * (1.0f / 3072.0f);

    float s2 = 0.f;
#pragma unroll
    for (int i = 0; i < 12; ++i) { float d = v[i] - mu; s2 += d * d; }
#pragma unroll
    for (int o = 32; o > 0; o >>= 1) s2 += __shfl_xor(s2, o);
    if ((tid & 63) == 0) rb[4 + (tid >> 6)] = s2;
    __syncthreads();
    float var = (rb[4] + rb[5] + rb[6] + rb[7]) * (1.0f / 3072.0f);
    float rstd = 1.0f / sqrtf(var + 1e-6f);

#pragma unroll
    for (int i = 0; i < 12; ++i)
        v[i] = (v[i] - mu) * rstd * gamma[tid + i * 256] + beta[tid + i * 256];

    // FWHT group 1: bits 8-11 (register index i)
#pragma unroll
    for (int b = 1; b < 16; b <<= 1) {
#pragma unroll
        for (int i = 0; i < 16; ++i) {
            if (!(i & b)) {
                float a0 = v[i], b0 = v[i | b];
                v[i] = a0 + b0;
                v[i | b] = a0 - b0;
            }
        }
    }
    // group 2: bits 0-5 (lane) via shfl_xor
#pragma unroll
    for (int m = 1; m <= 32; m <<= 1) {
#pragma unroll
        for (int i = 0; i < 16; ++i) {
            float p = __shfl_xor(v[i], m);
            v[i] = (lane & m) ? (p - v[i]) : (v[i] + p);
        }
    }
    // group 3: bits 6-7 (wave id) via LDS
#pragma unroll
    for (int m = 64; m <= 128; m <<= 1) {
        __syncthreads();
#pragma unroll
        for (int i = 0; i < 16; ++i) s[tid + i * 256] = v[i];
        __syncthreads();
#pragma unroll
        for (int i = 0; i < 16; ++i) {
            float p = s[(tid ^ m) + i * 256];
            v[i] = (tid & m) ? (p - v[i]) : (v[i] + p);
        }
    }

    // absmax of fwht/64
    float mx = 0.f;
#pragma unroll
    for (int i = 0; i < 16; ++i) mx = fmaxf(mx, fabsf(v[i]));
#pragma unroll
    for (int o = 32; o > 0; o >>= 1) mx = fmaxf(mx, __shfl_xor(mx, o));
    __syncthreads();
    if ((tid & 63) == 0) rb[tid >> 6] = mx;
    __syncthreads();
    float amraw = fmaxf(fmaxf(rb[0], rb[1]), fmaxf(rb[2], rb[3]));
    float amax = fmaxf(amraw * (1.0f / 64.0f), 1e-5f);
    float scale = 127.0f / amax;
    if (tid == 0) ainv[t] = amax * (1.0f / 127.0f);

    signed char* qr = q + (size_t)t * PAD_F;
#pragma unroll
    for (int i = 0; i < 16; ++i) {
        int qi = (int)rintf(v[i] * (1.0f / 64.0f) * scale);
        qi = max(-128, min(127, qi));
        qr[tid + i * 256] = (signed char)qi;
    }
}

// ---------------- int8 MFMA GEMM, 256x256 tile, BK=64 ----------------
// out[m][n] = (sum_k q[m][k]*t[n][k]) * wsc * ainv[m]
// ROUND 10: B-operand DIRECT global->register (skips LDS entirely for B):
//   - LDS traffic/tile: 128 KB -> 80 KB (A reads 64K + A staging writes 16K)
//   - B fragment = 16 rows x 64B = 16 full cache lines, L2-resident panel
//     (bm-inner-4 XCD swizzle), loaded 1 tile ahead, no barrier needed.
// A path unchanged from round 6 (verified 0 bank conflicts): paired-row LDS
// (row r holds matrix rows {2r,2r+1}, chunk (par,h) at slot (par*4+h)^(r&7)),
// pre-swizzled global source (rule #21), ring-4 buffers, 1 barrier/tile,
// counted vmcnt: 6 vmem/iter (2 A-stage + 4 B-gather) -> VMW(6), peel 4->0.
#define BK 64
#define NT (K_DIM / BK)   // 64

#define VMW(n) asm volatile("s_waitcnt vmcnt(" #n ")" ::: "memory")
#define SB0()  __builtin_amdgcn_sched_barrier(0)

__global__ __launch_bounds__(512, 2) void k_gemm(const signed char* __restrict__ Aq,
                                                 const signed char* __restrict__ Wq,
                                                 const float* __restrict__ ainv,
                                                 const float* __restrict__ wsp,
                                                 float* __restrict__ out) {
    __shared__ signed char sA[4][128 * 128];   // 4 x 16 KB (A: 256 rows -> 128 LDS-rows)

    int tid = threadIdx.x;
    int lane = tid & 63, wid = tid >> 6;

    // XCD partition: XCD x owns bm in {4x..4x+3} (A L2-resident), sweeps bn;
    // bm-inner-4 keeps each B panel hot for 4 consecutive blocks.
    int bid = blockIdx.x;
    int xcd = bid & 7, li = bid >> 3;
    int bmb = xcd * 4 + (li & 3);
    int bnb = li >> 2;
    size_t bm0 = (size_t)bmb * 256, bn0 = (size_t)bnb * 256;

    int wm = wid >> 2, wn = wid & 3;          // 2M x 4N waves; wave tile 128x64

    // ---- A staging decode (round-6 verified): lane l -> byte l*16 of 1KB seg ----
    int rr = lane >> 3, pp = lane & 7;
    int Lg = pp ^ rr;
    int spar = Lg >> 2, sh = Lg & 3;
    const signed char* gA = Aq + (bm0 + (size_t)(wid * 32 + 2 * rr + spar)) * K_DIM + sh * 16;

    // ---- A fragment read constants (16x16x64: frag row fr, kseg hh) ----
    int fr = lane & 15, hh = lane >> 4;       // hh in [0,4): K-chunk 16B
    int pos = (((fr & 1) << 2) | hh) ^ (fr >> 1);
    int abase = (wm * 64 + (fr >> 1)) * 8 + pos;   // + mf*64

    // ---- B direct-load pointers: lane reads B[row][k0 + hh*16 .. +16) ----
    const signed char* bp0 = Wq + (bn0 + (size_t)(wn * 64 +  0 + fr)) * K_DIM + hh * 16;
    const signed char* bp1 = Wq + (bn0 + (size_t)(wn * 64 + 16 + fr)) * K_DIM + hh * 16;
    const signed char* bp2 = Wq + (bn0 + (size_t)(wn * 64 + 32 + fr)) * K_DIM + hh * 16;
    const signed char* bp3 = Wq + (bn0 + (size_t)(wn * 64 + 48 + fr)) * K_DIM + hh * 16;

    i32x4 acc[8][4];
#pragma unroll
    for (int m = 0; m < 8; ++m)
#pragma unroll
        for (int n = 0; n < 4; ++n) acc[m][n] = (i32x4){0, 0, 0, 0};

    i32x4 afA[8], afB[8], bfA[4], bfB[4];

    auto STAGE = [&](int b, int t) {
        size_t k0 = (size_t)t * BK;
        gload_lds16(gA + k0, &sA[b][(wid * 16) * 128]);
        gload_lds16(gA + k0 + (size_t)16 * K_DIM, &sA[b][(wid * 16 + 8) * 128]);
    };

#define LOADB(T, BF) do {                                               \
    size_t k0 = (size_t)(T) * BK;                                       \
    BF[0] = *(const i32x4*)(bp0 + k0);                                  \
    BF[1] = *(const i32x4*)(bp1 + k0);                                  \
    BF[2] = *(const i32x4*)(bp2 + k0);                                  \
    BF[3] = *(const i32x4*)(bp3 + k0);                                  \
} while (0)

#define LOADFA(B, AF) do {                                              \
    const i32x4* va = (const i32x4*)&sA[B][0];                          \
    _Pragma("unroll")                                                   \
    for (int mf = 0; mf < 8; ++mf) AF[mf] = va[abase + mf * 64];        \
} while (0)

#define COMPUTE(AF, BF) do {                                            \
    __builtin_amdgcn_s_setprio(1);                                      \
    _Pragma("unroll")                                                   \
    for (int mf = 0; mf < 8; ++mf)                                      \
        _Pragma("unroll")                                               \
        for (int nf = 0; nf < 4; ++nf)                                  \
            acc[mf][nf] = __builtin_amdgcn_mfma_i32_16x16x64_i8(        \
                AF[mf], BF[nf], acc[mf][nf], 0, 0, 0);                  \
    __builtin_amdgcn_s_setprio(0);                                      \
} while (0)

// Per tile T: stage A(T+2); gather B(T+1)->regs; VMW(6) certifies A(T+1),B(T);
// barrier publishes A(T+1) cross-wave; ds_read A(T+1); MFMA(T).
#define BODY(T, AFC, BFC, AFN, BFN) do {                                \
    STAGE((T + 2) & 3, T + 2);                                          \
    LOADB(T + 1, BFN);                                                  \
    VMW(6);                                                             \
    SB0();                                                              \
    __builtin_amdgcn_s_barrier();                                       \
    SB0();                                                              \
    LOADFA((T + 1) & 3, AFN);                                           \
    COMPUTE(AFC, BFC);                                                  \
    asm volatile("s_waitcnt lgkmcnt(0)" ::: "memory");                  \
    SB0();                                                              \
} while (0)

    // prologue: B(0)->bfA; stage A tiles 0,1; certify B(0)+A(0); frags(0)->afA
    LOADB(0, bfA);
    STAGE(0, 0);
    STAGE(1, 1);
    VMW(2);                 // leaves A(1) in flight; B(0), A(0) landed
    SB0();
    __builtin_amdgcn_s_barrier();
    SB0();
    LOADFA(0, afA);
    asm volatile("s_waitcnt lgkmcnt(0)" ::: "memory");
    SB0();

#pragma unroll 1
    for (int t = 0; t < NT - 2; t += 2) {       // t = 0..60, bodies 0..61
        BODY(t, afA, bfA, afB, bfB);
        BODY(t + 1, afB, bfB, afA, bfA);
    }
    // t = 62: in-flight <=6 [A(63)x2, B(62)x4]; gather B(63); VMW(4) certifies
    // B(62)+A(63); barrier publishes A(63); read A(63); compute 62.
    LOADB(63, bfB);
    VMW(4);
    SB0();
    __builtin_amdgcn_s_barrier();
    SB0();
    LOADFA(3, afB);
    COMPUTE(afA, bfA);
    asm volatile("s_waitcnt lgkmcnt(0)" ::: "memory");
    SB0();
    // t = 63
    VMW(0);
    SB0();
    COMPUTE(afB, bfB);

    // epilogue: 16x16 C/D layout: col = lane&15, row = (lane>>4)*4 + reg
    float wsc = wsp[0];
#pragma unroll
    for (int mf = 0; mf < 8; ++mf) {
        size_t row0 = bm0 + wm * 128 + mf * 16 + hh * 4;
#pragma unroll
        for (int r = 0; r < 4; ++r) {
            size_t row = row0 + r;
            float sa = wsc * ainv[row];
#pragma unroll
            for (int nf = 0; nf < 4; ++nf) {
                size_t col = bn0 + wn * 64 + nf * 16 + fr;
                out[row * N_OUT + col] = (float)acc[mf][nf][r] * sa;
            }
        }
    }
#undef LOADB
#undef LOADFA
#undef COMPUTE
#undef BODY
}

extern "C" void kernel_launch(void* const* d_in, const int* in_sizes, int n_in,
                              void* d_out, int out_size, void* d_ws, size_t ws_size,
                              hipStream_t stream) {
    const float* x     = (const float*)d_in[0];
    const float* gamma = (const float*)d_in[1];
    const float* beta  = (const float*)d_in[2];
    const float* w     = (const float*)d_in[3];
    float* out = (float*)d_out;
    char* ws = (char*)d_ws;

    signed char* q   = (signed char*)(ws + Q_OFF);
    signed char* wq  = (signed char*)(ws + WQ_OFF);
    float* ainv      = (float*)(ws + AINV_OFF);
    float* partial   = (float*)(ws + PART_OFF);
    float* wsp       = (float*)(ws + WSC_OFF);

    k_wabs<<<dim3(4096), dim3(256), 0, stream>>>(w, partial);
    k_wscale<<<dim3(1), dim3(256), 0, stream>>>(partial, wsp);
    k_wquant<<<dim3(16384), dim3(256), 0, stream>>>(w, wsp, (unsigned int*)wq);
    k_lnfwht<<<dim3(TOKENS), dim3(256), 0, stream>>>(x, gamma, beta, q, ainv);
    k_gemm<<<dim3(512), dim3(512), 0, stream>>>(q, wq, ainv, wsp, out);
}